// Round 1
// baseline (177.714 us; speedup 1.0000x reference)
//
#include <hip/hip_runtime.h>

// Problem constants (from reference): B=16, L=512, D=512, T=4096, P=4
constexpr int Bn = 16;
constexpr int Ln = 512;
constexpr int Dn = 512;
constexpr int Tn = 4096;
constexpr int Pn = 4;

// Kernel 1: per-batch inclusive cumsum of durations (LDS Hillis-Steele scan),
// then scatter token index l into idx_map for frames t in [cum[l-1], cum[l]).
// Frames >= cum[L-1] keep the -1 sentinel (output zeros for the D part).
__global__ __launch_bounds__(Ln) void cumsum_scatter_kernel(
    const int* __restrict__ durations, int* __restrict__ idx_map) {
    const int b = blockIdx.x;
    const int l = threadIdx.x;  // 0..511

    __shared__ int cum[Ln];
    cum[l] = durations[b * Ln + l];
    __syncthreads();
    // Hillis-Steele inclusive scan
    for (int off = 1; off < Ln; off <<= 1) {
        int v = (l >= off) ? cum[l - off] : 0;
        __syncthreads();
        cum[l] += v;
        __syncthreads();
    }

    // init the frame->token map for this batch (ws is poisoned each call)
    for (int t = l; t < Tn; t += Ln) idx_map[b * Tn + t] = -1;
    __syncthreads();

    const int excl = (l > 0) ? cum[l - 1] : 0;
    const int incl = cum[l];
    const int start = min(excl, Tn);
    const int end   = min(incl, Tn);
    for (int t = start; t < end; ++t) idx_map[b * Tn + t] = l;
}

// Kernel 2: one block per output row (b,t). 128 threads each move one float4
// of the encoder row (512 f32); lane 0 appends the 4-float frame position.
// Row stride = 516 f32 = 2064 B = 129 * 16 B, so every float4 is aligned.
__global__ __launch_bounds__(128) void expand_kernel(
    const float* __restrict__ enc, const float* __restrict__ fpos,
    const int* __restrict__ idx_map, float* __restrict__ out) {
    const int row  = blockIdx.x;   // b*Tn + t
    const int b    = row >> 12;    // Tn = 4096 = 2^12
    const int lane = threadIdx.x;  // 0..127

    const int idx = idx_map[row];

    float4 v = make_float4(0.f, 0.f, 0.f, 0.f);
    if (idx >= 0) {
        const float4* src =
            reinterpret_cast<const float4*>(enc + (size_t)(b * Ln + idx) * Dn);
        v = src[lane];
    }

    float4* dst = reinterpret_cast<float4*>(out + (size_t)row * (Dn + Pn));
    dst[lane] = v;
    if (lane == 0) {
        dst[Dn / 4] = reinterpret_cast<const float4*>(fpos)[row];
    }
}

extern "C" void kernel_launch(void* const* d_in, const int* in_sizes, int n_in,
                              void* d_out, int out_size, void* d_ws, size_t ws_size,
                              hipStream_t stream) {
    const float* enc  = (const float*)d_in[0];  // [B, L, D] f32
    const int*   dur  = (const int*)d_in[1];    // [B, L] i32
    const float* fpos = (const float*)d_in[2];  // [B, T, P] f32
    // d_in[3] = input_lengths, unused by the reference computation

    float* out = (float*)d_out;                 // [B, T, D+P] f32
    int* idx_map = (int*)d_ws;                  // [B, T] i32 = 256 KB scratch

    cumsum_scatter_kernel<<<Bn, Ln, 0, stream>>>(dur, idx_map);
    expand_kernel<<<Bn * Tn, 128, 0, stream>>>(enc, fpos, idx_map, out);
}

// Round 2
// 166.463 us; speedup vs baseline: 1.0676x; 1.0676x over previous
//
#include <hip/hip_runtime.h>

// Problem constants (from reference): B=16, L=512, D=512, T=4096, P=4
constexpr int Bn = 16;
constexpr int Ln = 512;
constexpr int Dn = 512;
constexpr int Tn = 4096;
constexpr int Pn = 4;

constexpr int ROW_F4 = (Dn + Pn) / 4;          // 129 float4 per output row
constexpr int TOTAL_F4 = Bn * Tn * ROW_F4;     // 8,454,144 float4 total

// Kernel 1: per-batch inclusive cumsum of durations (LDS Hillis-Steele scan),
// then scatter token index l into idx_map for frames t in [cum[l-1], cum[l]).
// Frames >= cum[L-1] keep the -1 sentinel (output zeros for the D part).
__global__ __launch_bounds__(Ln) void cumsum_scatter_kernel(
    const int* __restrict__ durations, int* __restrict__ idx_map) {
    const int b = blockIdx.x;
    const int l = threadIdx.x;  // 0..511

    __shared__ int cum[Ln];
    cum[l] = durations[b * Ln + l];
    __syncthreads();
    // Hillis-Steele inclusive scan
    for (int off = 1; off < Ln; off <<= 1) {
        int v = (l >= off) ? cum[l - off] : 0;
        __syncthreads();
        cum[l] += v;
        __syncthreads();
    }

    // init the frame->token map for this batch (ws is poisoned each call)
    for (int t = l; t < Tn; t += Ln) idx_map[b * Tn + t] = -1;
    __syncthreads();

    const int excl = (l > 0) ? cum[l - 1] : 0;
    const int incl = cum[l];
    const int start = min(excl, Tn);
    const int end   = min(incl, Tn);
    for (int t = start; t < end; ++t) idx_map[b * Tn + t] = l;
}

// Kernel 2: flattened streaming expand. One thread per output float4 over the
// whole [B*T*(D+P)] array -> stores are one contiguous, line-aligned stream.
// row = g/129 (const-div -> mul+shift), c4 = g%129. c4<128 gathers from the
// encoder row (L2-resident, 1 MB/batch); c4==128 copies the frame position.
__global__ __launch_bounds__(256) void expand_flat_kernel(
    const float4* __restrict__ enc4, const float4* __restrict__ fpos4,
    const int* __restrict__ idx_map, float4* __restrict__ out4) {
    const int g = blockIdx.x * 256 + threadIdx.x;   // grid sized exactly
    const int row = g / ROW_F4;                     // b*Tn + t
    const int c4  = g - row * ROW_F4;               // 0..128
    const int b   = row >> 12;                      // Tn = 4096 = 2^12

    float4 v = make_float4(0.f, 0.f, 0.f, 0.f);
    if (c4 == ROW_F4 - 1) {
        v = fpos4[row];
    } else {
        const int idx = idx_map[row];
        if (idx >= 0) {
            // enc float4 index: (b*Ln + idx) * (Dn/4) + c4
            v = enc4[(size_t)((b << 9) + idx) * (Dn / 4) + c4];
        }
    }
    out4[g] = v;
}

extern "C" void kernel_launch(void* const* d_in, const int* in_sizes, int n_in,
                              void* d_out, int out_size, void* d_ws, size_t ws_size,
                              hipStream_t stream) {
    const float* enc  = (const float*)d_in[0];  // [B, L, D] f32
    const int*   dur  = (const int*)d_in[1];    // [B, L] i32
    const float* fpos = (const float*)d_in[2];  // [B, T, P] f32
    // d_in[3] = input_lengths, unused by the reference computation

    float* out = (float*)d_out;                 // [B, T, D+P] f32
    int* idx_map = (int*)d_ws;                  // [B, T] i32 = 256 KB scratch

    cumsum_scatter_kernel<<<Bn, Ln, 0, stream>>>(dur, idx_map);

    static_assert(TOTAL_F4 % 256 == 0, "grid sizing");
    expand_flat_kernel<<<TOTAL_F4 / 256, 256, 0, stream>>>(
        (const float4*)enc, (const float4*)fpos, idx_map, (float4*)out);
}

// Round 3
// 162.482 us; speedup vs baseline: 1.0937x; 1.0245x over previous
//
#include <hip/hip_runtime.h>

// Problem constants (from reference): B=16, L=512, D=512, T=4096, P=4
constexpr int Bn = 16;
constexpr int Ln = 512;
constexpr int Dn = 512;
constexpr int Tn = 4096;
constexpr int Pn = 4;

constexpr int ROW_F4 = (Dn + Pn) / 4;          // 129 float4 per output row
constexpr int TOTAL_F4 = Bn * Tn * ROW_F4;     // 8,454,144 float4 total
constexpr int NBLK = TOTAL_F4 / 256;           // 33,024 blocks
constexpr int NXCD = 8;
constexpr int BLK_PER_XCD = NBLK / NXCD;       // 4,128 = exactly 2 batches

// Kernel 1: per-batch inclusive cumsum of durations (LDS Hillis-Steele scan),
// then scatter token index l into idx_map for frames t in [cum[l-1], cum[l]).
// Frames >= cum[L-1] keep the -1 sentinel (output zeros for the D part).
__global__ __launch_bounds__(Ln) void cumsum_scatter_kernel(
    const int* __restrict__ durations, int* __restrict__ idx_map) {
    const int b = blockIdx.x;
    const int l = threadIdx.x;  // 0..511

    __shared__ int cum[Ln];
    cum[l] = durations[b * Ln + l];
    __syncthreads();
    // Hillis-Steele inclusive scan
    for (int off = 1; off < Ln; off <<= 1) {
        int v = (l >= off) ? cum[l - off] : 0;
        __syncthreads();
        cum[l] += v;
        __syncthreads();
    }

    // init the frame->token map for this batch (ws is poisoned each call)
    for (int t = l; t < Tn; t += Ln) idx_map[b * Tn + t] = -1;
    __syncthreads();

    const int excl = (l > 0) ? cum[l - 1] : 0;
    const int incl = cum[l];
    const int start = min(excl, Tn);
    const int end   = min(incl, Tn);
    for (int t = start; t < end; ++t) idx_map[b * Tn + t] = l;
}

// Kernel 2: flattened streaming expand with XCD-aware swizzle.
// Blocks dispatch round-robin across 8 XCDs (block i -> XCD i%8); remapping
// work = (blockIdx%8)*BLK_PER_XCD + blockIdx/8 gives each XCD a contiguous
// 2-batch region, so its private 4 MiB L2 holds the 2 MB enc working set
// instead of all XCDs re-fetching every batch (8x enc fetch amplification).
__global__ __launch_bounds__(256) void expand_flat_kernel(
    const float4* __restrict__ enc4, const float4* __restrict__ fpos4,
    const int* __restrict__ idx_map, float4* __restrict__ out4) {
    const int xcd = blockIdx.x & (NXCD - 1);
    const int j   = blockIdx.x >> 3;
    const int g   = (xcd * BLK_PER_XCD + j) * 256 + threadIdx.x;

    const int row = g / ROW_F4;                     // b*Tn + t
    const int c4  = g - row * ROW_F4;               // 0..128
    const int b   = row >> 12;                      // Tn = 4096 = 2^12

    float4 v = make_float4(0.f, 0.f, 0.f, 0.f);
    if (c4 == ROW_F4 - 1) {
        v = fpos4[row];
    } else {
        const int idx = idx_map[row];
        if (idx >= 0) {
            // enc float4 index: (b*Ln + idx) * (Dn/4) + c4
            v = enc4[(size_t)((b << 9) + idx) * (Dn / 4) + c4];
        }
    }
    out4[g] = v;
}

extern "C" void kernel_launch(void* const* d_in, const int* in_sizes, int n_in,
                              void* d_out, int out_size, void* d_ws, size_t ws_size,
                              hipStream_t stream) {
    const float* enc  = (const float*)d_in[0];  // [B, L, D] f32
    const int*   dur  = (const int*)d_in[1];    // [B, L] i32
    const float* fpos = (const float*)d_in[2];  // [B, T, P] f32
    // d_in[3] = input_lengths, unused by the reference computation

    float* out = (float*)d_out;                 // [B, T, D+P] f32
    int* idx_map = (int*)d_ws;                  // [B, T] i32 = 256 KB scratch

    cumsum_scatter_kernel<<<Bn, Ln, 0, stream>>>(dur, idx_map);

    static_assert(NBLK % NXCD == 0, "swizzle sizing");
    expand_flat_kernel<<<NBLK, 256, 0, stream>>>(
        (const float4*)enc, (const float4*)fpos, idx_map, (float4*)out);
}